// Round 5
// baseline (667.659 us; speedup 1.0000x reference)
//
#include <hip/hip_runtime.h>
#include <hip/hip_fp16.h>

// DepTreeLSTM on MI355X — persistent-block fused tree kernel.
// Each block owns 32 pairs and runs ALL 9 levels x both directions with only
// block-local barriers (state is block-private in ws; __syncthreads drains
// vmcnt -> same-CU visibility). Per (level,side): one M=64 x N=256 x K=384
// MFMA tile, A row = [x_node(320 fp16 table) || h_src(64 fp16 state)],
// B = [[W_iou|W_f];[U_iou|U_f]] (384x256 fp16, [col][k], gate-grouped cols).
// Staging via global_load_lds width=16 with XOR-8 granule swizzle.
// Root(up L8) = 4 rows/pair: [x||h7],[x||h9],[x||0],[0||0]; iou=r0+r1-r2.
// R4 bug fixed: ld_xb stores the RAW base pointer; the reader alone adds its
// per-lane swizzle offset koff (R4 double-added it -> permuted K-granules).

typedef _Float16 f16x8 __attribute__((ext_vector_type(8)));
typedef float f32x4 __attribute__((ext_vector_type(4)));

__device__ __forceinline__ void async16(const void* g, void* l) {
    __builtin_amdgcn_global_load_lds(
        (const __attribute__((address_space(1))) void*)g,
        (__attribute__((address_space(3))) void*)l, 16, 0, 0);
}

__device__ __forceinline__ float sigm(float x) { return 1.f / (1.f + __expf(-x)); }
__device__ __forceinline__ float ftanh(float x) {
    float a = __expf(-2.f * fabsf(x));
    return copysignf((1.f - a) / (1.f + a), x);
}

// ---- pack weights to fp16 [dir][col(256)][k(384)], gate-grouped cols ----
__global__ __launch_bounds__(256) void pack_weights(
    const float* __restrict__ Wi_u, const float* __restrict__ Ui_u,
    const float* __restrict__ Wf_u, const float* __restrict__ Uf_u,
    const float* __restrict__ Wi_d, const float* __restrict__ Ui_d,
    const float* __restrict__ Wf_d, const float* __restrict__ Uf_d,
    _Float16* __restrict__ Bt, _Float16* __restrict__ zp)
{
    int idx = blockIdx.x * 256 + threadIdx.x;   // 2*256*384 = 196608
    if (idx < 512) zp[idx] = (_Float16)0.f;
    int d   = idx / 98304;
    int rem = idx % 98304;
    int col = rem / 384;
    int k   = rem % 384;
    const float* Wi = d ? Wi_d : Wi_u;
    const float* Ui = d ? Ui_d : Ui_u;
    const float* Wf = d ? Wf_d : Wf_u;
    const float* Uf = d ? Uf_d : Uf_u;
    float v;
    if (col < 192) v = (k < 320) ? Wi[k * 192 + col] : Ui[(k - 320) * 192 + col];
    else {
        int c = col - 192;
        v = (k < 320) ? Wf[k * 64 + c] : Uf[(k - 320) * 64 + c];
    }
    Bt[idx] = (_Float16)v;
}

// ---- fuse+convert embeddings to fp16 x16[B*T][320] ----
__global__ __launch_bounds__(256) void build_x16(
    const float* __restrict__ tok, const float* __restrict__ oh,
    const float* __restrict__ dep, _Float16* __restrict__ x16)
{
    int idx = blockIdx.x * 256 + threadIdx.x;   // 16384 bt * 40 granules
    int bt = idx / 40, g = idx % 40;
    const float* src = (g < 32) ? tok + (size_t)bt * 256 + g * 8
                     : (g < 36) ? oh  + (size_t)bt * 32 + (g - 32) * 8
                                : dep + (size_t)bt * 32 + (g - 36) * 8;
    float4 f0 = *(const float4*)src;
    float4 f1 = *(const float4*)(src + 4);
    f16x8 v;
    v[0] = (_Float16)f0.x; v[1] = (_Float16)f0.y;
    v[2] = (_Float16)f0.z; v[3] = (_Float16)f0.w;
    v[4] = (_Float16)f1.x; v[5] = (_Float16)f1.y;
    v[6] = (_Float16)f1.z; v[7] = (_Float16)f1.w;
    *(f16x8*)(x16 + (size_t)bt * 320 + g * 8) = v;
}

// ---- one 64x256x384 tile: stage A+B, 6 k-tiles MFMA, LSTM epilogue ----
__device__ __forceinline__ void run_tile(
    _Float16* At, _Float16* Btl,
    const _Float16** ld_xb, const _Float16** ld_hb,
    const _Float16* __restrict__ x16,
    const int* __restrict__ nb, const int* __restrict__ nt,
    const _Float16* zp, float* __restrict__ out,
    const _Float16* __restrict__ B,
    float bi, float bo, float bu, float bff,
    _Float16* h_st, _Float16* c_st,
    int pair0, int rp_shift, int is_root,
    int p0, int p1, int hh0, int hh1, int oc0, int oc1,
    int tid, int w, int l15, int qd, int rsub, int koff, int colj)
{
    const int mask = (1 << rp_shift) - 1;

    if (tid < 64) {
        int pair = pair0 + (tid >> rp_shift);
        int slot = tid & mask;
        int pos, hp;
        if (is_root) { pos = (slot < 3) ? 8 : -1; hp = (slot == 0) ? 7 : (slot == 1) ? 9 : -1; }
        else         { pos = slot ? p1 : p0;      hp = slot ? hh1 : hh0; }
        const _Float16* xq = zp;
        if (pos >= 0) {
            int nd = pair * 16 + pos;
            xq = x16 + ((size_t)nb[nd] * 512 + nt[nd]) * 320;
        }
        ld_xb[tid] = xq;                       // RAW base; reader adds koff
        ld_hb[tid] = (hp < 0) ? zp : h_st + ((size_t)pair * 16 + hp) * 64;
    }
    __syncthreads();

    const _Float16* axb0 = ld_xb[w * 16 + rsub] + koff;
    const _Float16* axb1 = ld_xb[w * 16 + 8 + rsub] + koff;
    const _Float16* ahb0 = ld_hb[w * 16 + rsub] + koff;
    const _Float16* ahb1 = ld_hb[w * 16 + 8 + rsub] + koff;
    const _Float16* Bbase = B + (size_t)(w * 64 + rsub) * 384 + koff;

    f32x4 acc[4][4];
    #pragma unroll
    for (int i = 0; i < 4; ++i)
        #pragma unroll
        for (int j = 0; j < 4; ++j)
            acc[i][j] = (f32x4){0.f, 0.f, 0.f, 0.f};

    #pragma unroll
    for (int kt = 0; kt < 6; ++kt) {
        const _Float16* g0 = (kt < 5) ? (axb0 + kt * 64) : ahb0;
        const _Float16* g1 = (kt < 5) ? (axb1 + kt * 64) : ahb1;
        async16(g0, &At[(w * 16) * 64]);
        async16(g1, &At[(w * 16 + 8) * 64]);
        #pragma unroll
        for (int is = 0; is < 8; ++is)
            async16(Bbase + (size_t)is * 8 * 384 + kt * 64,
                    &Btl[(w * 64 + is * 8) * 64]);
        __syncthreads();

        #pragma unroll
        for (int s = 0; s < 2; ++s) {
            const int g0l = s * 4 + qd;
            f16x8 af[4];
            #pragma unroll
            for (int i = 0; i < 4; ++i) {
                int R = i * 16 + l15;
                af[i] = *(const f16x8*)&At[R * 64 + ((g0l + R) & 7) * 8];
            }
            #pragma unroll
            for (int j = 0; j < 4; ++j) {
                int C = j * 64 + w * 16 + l15;
                f16x8 bf = *(const f16x8*)&Btl[C * 64 + ((g0l + C) & 7) * 8];
                #pragma unroll
                for (int i = 0; i < 4; ++i)
                    acc[i][j] = __builtin_amdgcn_mfma_f32_16x16x32_f16(
                        af[i], bf, acc[i][j], 0, 0, 0);
            }
        }
        __syncthreads();
    }

    if (!is_root) {
        #pragma unroll
        for (int i = 0; i < 4; ++i) {
            #pragma unroll
            for (int r = 0; r < 4; ++r) {
                int R = i * 16 + qd * 4 + r;
                int pair = pair0 + (R >> 1);
                int slot = R & 1;
                int pos = slot ? p1 : p0;
                int hp  = slot ? hh1 : hh0;
                int oc  = slot ? oc1 : oc0;
                if (pos < 0 && oc < 0) continue;
                float I = acc[i][0][r] + bi;
                float O = acc[i][1][r] + bo;
                float U = acc[i][2][r] + bu;
                float F = acc[i][3][r] + bff;
                float cin = (hp >= 0)
                    ? (float)c_st[((size_t)pair * 16 + hp) * 64 + colj] : 0.f;
                float cn = sigm(I) * ftanh(U) + sigm(F) * cin;
                float h  = sigm(O) * ftanh(cn);
                if (oc >= 0) {
                    out[(size_t)pair * 192 + oc + colj] = h;
                } else {
                    size_t nd = ((size_t)pair * 16 + pos) * 64 + colj;
                    h_st[nd] = (_Float16)h;
                    c_st[nd] = (_Float16)cn;
                }
            }
        }
    } else {
        // slots: r0=[x||h7], r1=[x||h9], r2=[x||0], r3=[0||0]
        #pragma unroll
        for (int i = 0; i < 4; ++i) {
            int pair = pair0 + i * 4 + qd;
            float I  = acc[i][0][0] + acc[i][0][1] - acc[i][0][2] + bi;
            float O  = acc[i][1][0] + acc[i][1][1] - acc[i][1][2] + bo;
            float U  = acc[i][2][0] + acc[i][2][1] - acc[i][2][2] + bu;
            float F7 = acc[i][3][0] + bff;
            float F9 = acc[i][3][1] + bff;
            float c7 = (float)c_st[((size_t)pair * 16 + 7) * 64 + colj];
            float c9 = (float)c_st[((size_t)pair * 16 + 9) * 64 + colj];
            float cn = sigm(I) * ftanh(U) + sigm(F7) * c7 + sigm(F9) * c9;
            float h  = sigm(O) * ftanh(cn);
            out[(size_t)pair * 192 + colj] = h;
        }
    }
}

__global__ __launch_bounds__(256, 2) void tree_kernel(
    const _Float16* __restrict__ x16,
    const int* __restrict__ nb, const int* __restrict__ nt,
    const _Float16* __restrict__ zp,
    const _Float16* __restrict__ Bu, const _Float16* __restrict__ Bd,
    const float* __restrict__ bi_u, const float* __restrict__ bf_u,
    const float* __restrict__ bi_d, const float* __restrict__ bf_d,
    _Float16* h_u, _Float16* c_u, _Float16* h_d, _Float16* c_d,
    float* __restrict__ out)
{
    __shared__ _Float16 At[64 * 64];          // 8 KB
    __shared__ _Float16 Btl[256 * 64];        // 32 KB
    __shared__ const _Float16* ld_xb[64];
    __shared__ const _Float16* ld_hb[64];

    const int pair00 = blockIdx.x * 32;
    const int tid = threadIdx.x, lane = tid & 63, w = tid >> 6;
    const int l15 = lane & 15, qd = lane >> 4;
    const int rsub = lane >> 3, pg = lane & 7;
    const int koff = ((pg - rsub) & 7) * 8;
    const int colj = w * 16 + l15;

    const float biU = bi_u[colj], boU = bi_u[64 + colj],
                buU = bi_u[128 + colj], bfU = bf_u[colj];
    const float biD = bi_d[colj], boD = bi_d[64 + colj],
                buD = bi_d[128 + colj], bfD = bf_d[colj];

    for (int t = 0; t < 9; ++t) {
        // ---------- upward side ----------
        if (t < 8) {
            int p0 = t;
            int p1 = (t == 7) ? -1 : 15 - t;
            int h0 = t - 1;                           // t=0 -> -1
            int h1 = (t == 0 || t == 7) ? -1 : 16 - t;
            run_tile(At, Btl, ld_xb, ld_hb, x16, nb, nt, zp, out,
                     Bu, biU, boU, buU, bfU, h_u, c_u,
                     pair00, 1, 0, p0, p1, h0, h1, -1, -1,
                     tid, w, l15, qd, rsub, koff, colj);
        } else {
            #pragma unroll
            for (int c = 0; c < 2; ++c)
                run_tile(At, Btl, ld_xb, ld_hb, x16, nb, nt, zp, out,
                         Bu, biU, boU, buU, bfU, h_u, c_u,
                         pair00 + c * 16, 2, 1, 8, 8, 7, 9, -1, -1,
                         tid, w, l15, qd, rsub, koff, colj);
        }
        // ---------- downward side ----------
        {
            int p0 = 8 - t;
            int p1 = (t == 0 || t == 8) ? -1 : 8 + t;
            int h0 = (t == 0) ? -1 : 9 - t;
            int h1 = (t == 0 || t == 8) ? -1 : 7 + t;
            int oc0 = (t == 8) ? 64 : -1;
            int oc1 = (t == 7) ? 128 : -1;
            run_tile(At, Btl, ld_xb, ld_hb, x16, nb, nt, zp, out,
                     Bd, biD, boD, buD, bfD, h_d, c_d,
                     pair00, 1, 0, p0, p1, h0, h1, oc0, oc1,
                     tid, w, l15, qd, rsub, koff, colj);
        }
    }
}

extern "C" void kernel_launch(void* const* d_in, const int* in_sizes, int n_in,
                              void* d_out, int out_size, void* d_ws, size_t ws_size,
                              hipStream_t stream)
{
    const float* tok  = (const float*)d_in[0];
    const float* ohp  = (const float*)d_in[1];
    const float* dep  = (const float*)d_in[2];
    const int*   nb   = (const int*)d_in[3];
    const int*   nt   = (const int*)d_in[4];
    const float* Wi_u = (const float*)d_in[13];
    const float* Ui_u = (const float*)d_in[14];
    const float* bi_u = (const float*)d_in[15];
    const float* Wf_u = (const float*)d_in[16];
    const float* Uf_u = (const float*)d_in[17];
    const float* bf_u = (const float*)d_in[18];
    const float* Wi_d = (const float*)d_in[19];
    const float* Ui_d = (const float*)d_in[20];
    const float* bi_d = (const float*)d_in[21];
    const float* Wf_d = (const float*)d_in[22];
    const float* Uf_d = (const float*)d_in[23];
    const float* bf_d = (const float*)d_in[24];

    char* ws = (char*)d_ws;
    _Float16* Bt   = (_Float16*)(ws);                          // 384 KB
    _Float16* zp   = (_Float16*)(ws + (512 << 10));            // 1 KB zeros
    _Float16* x16  = (_Float16*)(ws + (1  << 20));             // 10.5 MB
    _Float16* h_u  = (_Float16*)(ws + (16 << 20));             // 32 MB each
    _Float16* c_u  = (_Float16*)(ws + (48 << 20));
    _Float16* h_d  = (_Float16*)(ws + (80 << 20));
    _Float16* c_d  = (_Float16*)(ws + (112 << 20));
    float* out = (float*)d_out;

    pack_weights<<<768, 256, 0, stream>>>(Wi_u, Ui_u, Wf_u, Uf_u,
                                          Wi_d, Ui_d, Wf_d, Uf_d, Bt, zp);
    build_x16<<<2560, 256, 0, stream>>>(tok, ohp, dep, x16);

    tree_kernel<<<512, 256, 0, stream>>>(x16, nb, nt, zp,
                                         Bt, Bt + 98304,
                                         bi_u, bf_u, bi_d, bf_d,
                                         h_u, c_u, h_d, c_d, out);
    (void)in_sizes; (void)n_in; (void)out_size; (void)ws_size;
}

// Round 6
// 508.296 us; speedup vs baseline: 1.3135x; 1.3135x over previous
//
#include <hip/hip_runtime.h>
#include <hip/hip_fp16.h>

// DepTreeLSTM on MI355X — R6: factor the projection by distinct (b,t).
// 1) build_x16: fused fp16 embeddings x16[16384][320].
// 2) xp_gemm: XP[bt][dir*256 + unit*4 + gate] fp16 = x16 @ W + b  (5.4 GFLOP,
//    16 MB table -> cache-resident). Gates interleaved per unit so a level
//    kernel reads all 4 preacts of its unit with one 8B load.
// 3) 9 level dispatches (up+down fused by grid split): NO LDS, NO barriers.
//    Per wave: B = U[64x256] slice in 32 loop-invariant VGPRs (8 f16x8),
//    A = h_src frags straight from global, acc initialized from gathered XP,
//    32 MFMA (16x16x32 f16), in-register LSTM epilogue.
//    State: ping-pong [pair][side(2)][64] fp16, 4 MB per buffer (L2-hot).
//    Root: A=(h7+h9) for i/o/u + separate F7/F9 chains (A=h7 / A=h9).

typedef _Float16 f16x8 __attribute__((ext_vector_type(8)));
typedef _Float16 f16x4 __attribute__((ext_vector_type(4)));
typedef float f32x4 __attribute__((ext_vector_type(4)));

__device__ __forceinline__ void async16(const void* g, void* l) {
    __builtin_amdgcn_global_load_lds(
        (const __attribute__((address_space(1))) void*)g,
        (__attribute__((address_space(3))) void*)l, 16, 0, 0);
}
__device__ __forceinline__ float sigm(float x) { return 1.f / (1.f + __expf(-x)); }
__device__ __forceinline__ float ftanh(float x) {
    float a = __expf(-2.f * fabsf(x));
    return copysignf((1.f - a) / (1.f + a), x);
}

// ---- pack: Bx[dir][col'=unit*4+gate][k320], Upk[dir][gate][unit][k64],
//            pb[dir][256] (bias, interleaved), zp (zeros) ----
__global__ __launch_bounds__(256) void pack_all(
    const float* __restrict__ Wi_u, const float* __restrict__ Ui_u,
    const float* __restrict__ bi_u, const float* __restrict__ Wf_u,
    const float* __restrict__ Uf_u, const float* __restrict__ bf_u,
    const float* __restrict__ Wi_d, const float* __restrict__ Ui_d,
    const float* __restrict__ bi_d, const float* __restrict__ Wf_d,
    const float* __restrict__ Uf_d, const float* __restrict__ bf_d,
    _Float16* __restrict__ Bx, _Float16* __restrict__ Upk,
    float* __restrict__ pb, _Float16* __restrict__ zp)
{
    int idx = blockIdx.x * 256 + threadIdx.x;     // 196608 total
    if (idx < 64) zp[idx] = (_Float16)0.f;
    if (idx < 512) {
        int d = idx >> 8, c = idx & 255, u = c >> 2, g = c & 3;
        const float* bio = d ? bi_d : bi_u;
        const float* bf  = d ? bf_d : bf_u;
        pb[idx] = (g < 3) ? bio[g * 64 + u] : bf[u];
    }
    if (idx < 163840) {                            // Bx: 2*256*320
        int d = idx / 81920, r1 = idx % 81920;
        int c = r1 / 320, k = r1 % 320, u = c >> 2, g = c & 3;
        const float* Wio = d ? Wi_d : Wi_u;
        const float* Wf  = d ? Wf_d : Wf_u;
        Bx[idx] = (_Float16)((g < 3) ? Wio[k * 192 + g * 64 + u] : Wf[k * 64 + u]);
    } else {                                       // Upk: 2*4*64*64 = 32768
        int j = idx - 163840;
        int d = j >> 14, r2 = j & 16383;
        int g = r2 >> 12, u = (r2 >> 6) & 63, k = r2 & 63;
        const float* Uio = d ? Ui_d : Ui_u;
        const float* Uf  = d ? Uf_d : Uf_u;
        Upk[j] = (_Float16)((g < 3) ? Uio[k * 192 + g * 64 + u] : Uf[k * 64 + u]);
    }
}

// ---- fuse+convert embeddings to fp16 x16[B*T][320] ----
__global__ __launch_bounds__(256) void build_x16(
    const float* __restrict__ tok, const float* __restrict__ oh,
    const float* __restrict__ dep, _Float16* __restrict__ x16)
{
    int idx = blockIdx.x * 256 + threadIdx.x;   // 16384 bt * 40 granules
    int bt = idx / 40, g = idx % 40;
    const float* src = (g < 32) ? tok + (size_t)bt * 256 + g * 8
                     : (g < 36) ? oh  + (size_t)bt * 32 + (g - 32) * 8
                                : dep + (size_t)bt * 32 + (g - 36) * 8;
    float4 f0 = *(const float4*)src;
    float4 f1 = *(const float4*)(src + 4);
    f16x8 v;
    v[0] = (_Float16)f0.x; v[1] = (_Float16)f0.y;
    v[2] = (_Float16)f0.z; v[3] = (_Float16)f0.w;
    v[4] = (_Float16)f1.x; v[5] = (_Float16)f1.y;
    v[6] = (_Float16)f1.z; v[7] = (_Float16)f1.w;
    *(f16x8*)(x16 + (size_t)bt * 320 + g * 8) = v;
}

// ---- XP = x16 @ Bx + pb : M=16384, K=320, N=256 per dir ----
__global__ __launch_bounds__(256) void xp_gemm(
    const _Float16* __restrict__ x16, const _Float16* __restrict__ Bx,
    const float* __restrict__ pb, _Float16* __restrict__ XP)
{
    __shared__ _Float16 At[128 * 64];     // 16 KB
    __shared__ _Float16 Btl[256 * 64];    // 32 KB
    const int mt = blockIdx.x & 127, dir = blockIdx.x >> 7;
    const int tid = threadIdx.x, lane = tid & 63, w = tid >> 6;
    const int l15 = lane & 15, qd = lane >> 4;
    const int rsub = lane >> 3, pg = lane & 7;
    const int koff = ((pg - rsub) & 7) * 8;
    const int rowbase = mt * 128;
    const _Float16* Bb = Bx + (size_t)dir * 81920 + (w * 64 + rsub) * 320 + koff;

    f32x4 acc[8][4];
    #pragma unroll
    for (int i = 0; i < 8; ++i)
        #pragma unroll
        for (int j = 0; j < 4; ++j) acc[i][j] = (f32x4){0.f, 0.f, 0.f, 0.f};

    #pragma unroll
    for (int kt = 0; kt < 5; ++kt) {
        #pragma unroll
        for (int is = 0; is < 4; ++is)
            async16(x16 + (size_t)(rowbase + w * 32 + is * 8 + rsub) * 320
                        + kt * 64 + koff,
                    &At[(w * 32 + is * 8) * 64]);
        #pragma unroll
        for (int is = 0; is < 8; ++is)
            async16(Bb + (size_t)is * 8 * 320 + kt * 64,
                    &Btl[(w * 64 + is * 8) * 64]);
        __syncthreads();
        #pragma unroll
        for (int s = 0; s < 2; ++s) {
            const int g0 = s * 4 + qd;
            f16x8 af[8];
            #pragma unroll
            for (int i = 0; i < 8; ++i) {
                int R = i * 16 + l15;
                af[i] = *(const f16x8*)&At[R * 64 + ((g0 + R) & 7) * 8];
            }
            #pragma unroll
            for (int j = 0; j < 4; ++j) {
                int C = j * 64 + w * 16 + l15;
                f16x8 bf = *(const f16x8*)&Btl[C * 64 + ((g0 + C) & 7) * 8];
                #pragma unroll
                for (int i = 0; i < 8; ++i)
                    acc[i][j] = __builtin_amdgcn_mfma_f32_16x16x32_f16(
                        af[i], bf, acc[i][j], 0, 0, 0);
            }
        }
        __syncthreads();
    }
    #pragma unroll
    for (int i = 0; i < 8; ++i)
        #pragma unroll
        for (int j = 0; j < 4; ++j) {
            int colp = j * 64 + w * 16 + l15;
            float bias = pb[dir * 256 + colp];
            #pragma unroll
            for (int r = 0; r < 4; ++r) {
                int row = rowbase + i * 16 + qd * 4 + r;
                XP[(size_t)row * 512 + dir * 256 + colp] =
                    (_Float16)(acc[i][j][r] + bias);
            }
        }
}

struct LSide {
    const _Float16* U;        // [gate(4)][unit(64)][k(64)] this dir
    const _Float16* pXP;      // XP + dir*256 (row stride 512)
    _Float16 *h_w, *c_w;
    const _Float16 *h_r, *c_r;     // prev-parity state
    const _Float16 *h_r2, *c_r2;   // root only: parity0 (pos 9)
    int rp_shift, is_root;
    int p0, p1, rd0, rd1, oc0, oc1;
};

__global__ __launch_bounds__(256) void level_kernel(
    const int* __restrict__ nb, const int* __restrict__ nt,
    const _Float16* __restrict__ zp,
    float* __restrict__ out, int Gu, LSide up, LSide dn)
{
    const int b = blockIdx.x;
    const bool isup = b < Gu;
    const LSide S = isup ? up : dn;
    const int rowbase = (isup ? b : b - Gu) * 64;
    const int tid = threadIdx.x, lane = tid & 63, w = tid >> 6;
    const int l15 = lane & 15, qd = lane >> 4;
    const int unit = w * 16 + l15;
    const int mask = (1 << S.rp_shift) - 1;

    f16x8 bfr[2][4];
    #pragma unroll
    for (int s = 0; s < 2; ++s)
        #pragma unroll
        for (int g = 0; g < 4; ++g)
            bfr[s][g] = *(const f16x8*)(S.U + (g * 64 + unit) * 64 + s * 32 + qd * 8);

    if (!S.is_root) {
        const _Float16* ap[4];
        #pragma unroll
        for (int i = 0; i < 4; ++i) {
            int row = rowbase + i * 16 + l15;
            int pair = row >> S.rp_shift, slot = row & mask;
            int rs = slot ? S.rd1 : S.rd0;
            ap[i] = (rs < 0) ? zp : S.h_r + (size_t)(pair * 2 + rs) * 64;
        }
        f32x4 acc[4][4];
        #pragma unroll
        for (int i = 0; i < 4; ++i)
            #pragma unroll
            for (int r = 0; r < 4; ++r) {
                int row = rowbase + i * 16 + qd * 4 + r;
                int pair = row >> S.rp_shift, slot = row & mask;
                int pos = slot ? S.p1 : S.p0;
                int node = pair * 16 + pos;
                int bt = nb[node] * 512 + nt[node];
                f16x4 g4 = *(const f16x4*)(S.pXP + (size_t)bt * 512 + unit * 4);
                acc[i][0][r] = (float)g4[0];
                acc[i][1][r] = (float)g4[1];
                acc[i][2][r] = (float)g4[2];
                acc[i][3][r] = (float)g4[3];
            }
        #pragma unroll
        for (int s = 0; s < 2; ++s)
            #pragma unroll
            for (int i = 0; i < 4; ++i) {
                f16x8 af = *(const f16x8*)(ap[i] + s * 32 + qd * 8);
                #pragma unroll
                for (int g = 0; g < 4; ++g)
                    acc[i][g] = __builtin_amdgcn_mfma_f32_16x16x32_f16(
                        af, bfr[s][g], acc[i][g], 0, 0, 0);
            }
        #pragma unroll
        for (int i = 0; i < 4; ++i)
            #pragma unroll
            for (int r = 0; r < 4; ++r) {
                int row = rowbase + i * 16 + qd * 4 + r;
                int pair = row >> S.rp_shift, slot = row & mask;
                int rs = slot ? S.rd1 : S.rd0;
                int oc = slot ? S.oc1 : S.oc0;
                float I = acc[i][0][r], O = acc[i][1][r],
                      Uu = acc[i][2][r], F = acc[i][3][r];
                float cin = (rs >= 0)
                    ? (float)S.c_r[(size_t)(pair * 2 + rs) * 64 + unit] : 0.f;
                float cn = sigm(I) * ftanh(Uu) + sigm(F) * cin;
                float h = sigm(O) * ftanh(cn);
                if (oc >= 0) {
                    out[(size_t)pair * 192 + oc + unit] = h;
                } else {
                    size_t sa = (size_t)(pair * 2 + slot) * 64 + unit;
                    S.h_w[sa] = (_Float16)h;
                    S.c_w[sa] = (_Float16)cn;
                }
            }
    } else {
        // root: one row per pair; A=(h7+h9) for i/o/u; F7 (A=h7), F9 (A=h9)
        const _Float16 *a7[4], *a9[4];
        #pragma unroll
        for (int i = 0; i < 4; ++i) {
            int pair = rowbase + i * 16 + l15;
            a7[i] = S.h_r  + (size_t)(pair * 2 + 0) * 64;
            a9[i] = S.h_r2 + (size_t)(pair * 2 + 1) * 64;
        }
        f32x4 acc[4][3], aF7[4], aF9[4];
        #pragma unroll
        for (int i = 0; i < 4; ++i)
            #pragma unroll
            for (int r = 0; r < 4; ++r) {
                int pair = rowbase + i * 16 + qd * 4 + r;
                int node = pair * 16 + 8;
                int bt = nb[node] * 512 + nt[node];
                f16x4 g4 = *(const f16x4*)(S.pXP + (size_t)bt * 512 + unit * 4);
                acc[i][0][r] = (float)g4[0];
                acc[i][1][r] = (float)g4[1];
                acc[i][2][r] = (float)g4[2];
                aF7[i][r] = (float)g4[3];
                aF9[i][r] = (float)g4[3];
            }
        #pragma unroll
        for (int s = 0; s < 2; ++s)
            #pragma unroll
            for (int i = 0; i < 4; ++i) {
                f16x8 v7 = *(const f16x8*)(a7[i] + s * 32 + qd * 8);
                f16x8 v9 = *(const f16x8*)(a9[i] + s * 32 + qd * 8);
                f16x8 vs = v7 + v9;
                acc[i][0] = __builtin_amdgcn_mfma_f32_16x16x32_f16(vs, bfr[s][0], acc[i][0], 0, 0, 0);
                acc[i][1] = __builtin_amdgcn_mfma_f32_16x16x32_f16(vs, bfr[s][1], acc[i][1], 0, 0, 0);
                acc[i][2] = __builtin_amdgcn_mfma_f32_16x16x32_f16(vs, bfr[s][2], acc[i][2], 0, 0, 0);
                aF7[i]    = __builtin_amdgcn_mfma_f32_16x16x32_f16(v7, bfr[s][3], aF7[i], 0, 0, 0);
                aF9[i]    = __builtin_amdgcn_mfma_f32_16x16x32_f16(v9, bfr[s][3], aF9[i], 0, 0, 0);
            }
        #pragma unroll
        for (int i = 0; i < 4; ++i)
            #pragma unroll
            for (int r = 0; r < 4; ++r) {
                int pair = rowbase + i * 16 + qd * 4 + r;
                float c7 = (float)S.c_r [(size_t)(pair * 2 + 0) * 64 + unit];
                float c9 = (float)S.c_r2[(size_t)(pair * 2 + 1) * 64 + unit];
                float cn = sigm(acc[i][0][r]) * ftanh(acc[i][2][r])
                         + sigm(aF7[i][r]) * c7 + sigm(aF9[i][r]) * c9;
                float h = sigm(acc[i][1][r]) * ftanh(cn);
                out[(size_t)pair * 192 + unit] = h;
            }
    }
}

extern "C" void kernel_launch(void* const* d_in, const int* in_sizes, int n_in,
                              void* d_out, int out_size, void* d_ws, size_t ws_size,
                              hipStream_t stream)
{
    const float* tok  = (const float*)d_in[0];
    const float* ohp  = (const float*)d_in[1];
    const float* dep  = (const float*)d_in[2];
    const int*   nb   = (const int*)d_in[3];
    const int*   nt   = (const int*)d_in[4];
    const float* Wi_u = (const float*)d_in[13];
    const float* Ui_u = (const float*)d_in[14];
    const float* bi_u = (const float*)d_in[15];
    const float* Wf_u = (const float*)d_in[16];
    const float* Uf_u = (const float*)d_in[17];
    const float* bf_u = (const float*)d_in[18];
    const float* Wi_d = (const float*)d_in[19];
    const float* Ui_d = (const float*)d_in[20];
    const float* bi_d = (const float*)d_in[21];
    const float* Wf_d = (const float*)d_in[22];
    const float* Uf_d = (const float*)d_in[23];
    const float* bf_d = (const float*)d_in[24];

    char* ws = (char*)d_ws;
    _Float16* Bx  = (_Float16*)(ws);                    // 320 KB
    _Float16* Upk = (_Float16*)(ws + 0x50000);          // 64 KB
    float*    pb  = (float*)   (ws + 0x60000);          // 2 KB
    _Float16* zp  = (_Float16*)(ws + 0x61000);          // 128 B
    _Float16* x16 = (_Float16*)(ws + (1u  << 20));      // 10 MB
    _Float16* XP  = (_Float16*)(ws + (12u << 20));      // 16 MB
    char*     stb = ws + (29u << 20);                   // 8 x 4 MB state
    float* out = (float*)d_out;

    auto st = [&](int d, int p, int hc) -> _Float16* {
        return (_Float16*)(stb + ((size_t)((d * 2 + p) * 2 + hc) << 22));
    };

    pack_all<<<768, 256, 0, stream>>>(Wi_u, Ui_u, bi_u, Wf_u, Uf_u, bf_u,
                                      Wi_d, Ui_d, bi_d, Wf_d, Uf_d, bf_d,
                                      Bx, Upk, pb, zp);
    build_x16<<<2560, 256, 0, stream>>>(tok, ohp, dep, x16);
    xp_gemm<<<256, 256, 0, stream>>>(x16, Bx, pb, XP);

    static const int Gu[9] = {512,512,512,512,512,512,512,256,256};
    static const int Gd[9] = {256,512,512,512,512,512,512,512,256};

    for (int t = 0; t < 9; ++t) {
        int p = t & 1, q = p ^ 1;
        LSide U, D;
        U.U = Upk;          U.pXP = XP;
        U.h_w = st(0,p,0);  U.c_w = st(0,p,1);
        U.h_r = st(0,q,0);  U.c_r = st(0,q,1);
        U.h_r2 = st(0,0,0); U.c_r2 = st(0,0,1);
        U.is_root = (t == 8);
        if (t < 7) { U.rp_shift = 1; U.p0 = t; U.p1 = 15 - t;
                     U.rd0 = t ? 0 : -1; U.rd1 = t ? 1 : -1;
                     U.oc0 = -1; U.oc1 = -1; }
        else       { U.rp_shift = 0; U.p0 = 7; U.p1 = 7;
                     U.rd0 = 0; U.rd1 = 0; U.oc0 = -1; U.oc1 = -1; }

        D.U = Upk + 16384;  D.pXP = XP + 256;
        D.h_w = st(1,p,0);  D.c_w = st(1,p,1);
        D.h_r = st(1,q,0);  D.c_r = st(1,q,1);
        D.h_r2 = D.h_r;     D.c_r2 = D.c_r;
        D.is_root = 0;
        if (t == 0)      { D.rp_shift = 0; D.p0 = 8; D.p1 = 8;
                           D.rd0 = -1; D.rd1 = -1; D.oc0 = -1; D.oc1 = -1; }
        else if (t == 8) { D.rp_shift = 0; D.p0 = 0; D.p1 = 0;
                           D.rd0 = 0; D.rd1 = 0; D.oc0 = 64; D.oc1 = 64; }
        else             { D.rp_shift = 1; D.p0 = 8 - t; D.p1 = 8 + t;
                           D.rd0 = 0; D.rd1 = (t == 1) ? 0 : 1;
                           D.oc0 = -1; D.oc1 = (t == 7) ? 128 : -1; }

        level_kernel<<<Gu[t] + Gd[t], 256, 0, stream>>>(nb, nt, zp, out,
                                                        Gu[t], U, D);
    }
    (void)in_sizes; (void)n_in; (void)out_size; (void)ws_size;
}

// Round 7
// 224.164 us; speedup vs baseline: 2.9784x; 2.2675x over previous
//
#include <hip/hip_runtime.h>
#include <hip/hip_fp16.h>

// DepTreeLSTM on MI355X — R7: single persistent tree dispatch, LDS state.
// Pipeline: pack_all (weights->fp16, gate-interleaved) ; build_x16 (fused
// fp16 embeddings [16384][320]) ; xp_gemm (XP[bt][dir*256+unit*4+gate] =
// x16 @ W + b, 16 MB cache-resident) ; tree_kernel (512 blocks x 32 pairs:
// all 9 levels x both dirs, frontier h/c state in LDS stride-68 rows,
// K=64 MFMA recurrence with register-resident B slice, 2 barriers/level).
// Root = A=(h7+h9) for i/o/u + separate F7/F9 MFMA chains.

typedef _Float16 f16x8 __attribute__((ext_vector_type(8)));
typedef _Float16 f16x4 __attribute__((ext_vector_type(4)));
typedef float f32x4 __attribute__((ext_vector_type(4)));

__device__ __forceinline__ void async16(const void* g, void* l) {
    __builtin_amdgcn_global_load_lds(
        (const __attribute__((address_space(1))) void*)g,
        (__attribute__((address_space(3))) void*)l, 16, 0, 0);
}
__device__ __forceinline__ float sigm(float x) {
    return __builtin_amdgcn_rcpf(1.f + __expf(-x));
}
__device__ __forceinline__ float ftanh(float x) {
    float a = __expf(-2.f * fabsf(x));
    return copysignf((1.f - a) * __builtin_amdgcn_rcpf(1.f + a), x);
}

// ---- pack: Bx[dir][col'=unit*4+gate][k320], Upk[dir][gate][unit][k64],
//            pb[dir][256] interleaved bias ----
__global__ __launch_bounds__(256) void pack_all(
    const float* __restrict__ Wi_u, const float* __restrict__ Ui_u,
    const float* __restrict__ bi_u, const float* __restrict__ Wf_u,
    const float* __restrict__ Uf_u, const float* __restrict__ bf_u,
    const float* __restrict__ Wi_d, const float* __restrict__ Ui_d,
    const float* __restrict__ bi_d, const float* __restrict__ Wf_d,
    const float* __restrict__ Uf_d, const float* __restrict__ bf_d,
    _Float16* __restrict__ Bx, _Float16* __restrict__ Upk,
    float* __restrict__ pb)
{
    int idx = blockIdx.x * 256 + threadIdx.x;     // 196608 total
    if (idx < 512) {
        int d = idx >> 8, c = idx & 255, u = c >> 2, g = c & 3;
        const float* bio = d ? bi_d : bi_u;
        const float* bf  = d ? bf_d : bf_u;
        pb[idx] = (g < 3) ? bio[g * 64 + u] : bf[u];
    }
    if (idx < 163840) {                            // Bx: 2*256*320
        int d = idx / 81920, r1 = idx % 81920;
        int c = r1 / 320, k = r1 % 320, u = c >> 2, g = c & 3;
        const float* Wio = d ? Wi_d : Wi_u;
        const float* Wf  = d ? Wf_d : Wf_u;
        Bx[idx] = (_Float16)((g < 3) ? Wio[k * 192 + g * 64 + u] : Wf[k * 64 + u]);
    } else {                                       // Upk: 2*4*64*64 = 32768
        int j = idx - 163840;
        int d = j >> 14, r2 = j & 16383;
        int g = r2 >> 12, u = (r2 >> 6) & 63, k = r2 & 63;
        const float* Uio = d ? Ui_d : Ui_u;
        const float* Uf  = d ? Uf_d : Uf_u;
        Upk[j] = (_Float16)((g < 3) ? Uio[k * 192 + g * 64 + u] : Uf[k * 64 + u]);
    }
}

// ---- fuse+convert embeddings to fp16 x16[B*T][320] ----
__global__ __launch_bounds__(256) void build_x16(
    const float* __restrict__ tok, const float* __restrict__ oh,
    const float* __restrict__ dep, _Float16* __restrict__ x16)
{
    int idx = blockIdx.x * 256 + threadIdx.x;   // 16384 bt * 40 granules
    int bt = idx / 40, g = idx % 40;
    const float* src = (g < 32) ? tok + (size_t)bt * 256 + g * 8
                     : (g < 36) ? oh  + (size_t)bt * 32 + (g - 32) * 8
                                : dep + (size_t)bt * 32 + (g - 36) * 8;
    float4 f0 = *(const float4*)src;
    float4 f1 = *(const float4*)(src + 4);
    f16x8 v;
    v[0] = (_Float16)f0.x; v[1] = (_Float16)f0.y;
    v[2] = (_Float16)f0.z; v[3] = (_Float16)f0.w;
    v[4] = (_Float16)f1.x; v[5] = (_Float16)f1.y;
    v[6] = (_Float16)f1.z; v[7] = (_Float16)f1.w;
    *(f16x8*)(x16 + (size_t)bt * 320 + g * 8) = v;
}

// ---- XP = x16 @ Bx + pb : M=16384, K=320, N=256 per dir ----
__global__ __launch_bounds__(256) void xp_gemm(
    const _Float16* __restrict__ x16, const _Float16* __restrict__ Bx,
    const float* __restrict__ pb, _Float16* __restrict__ XP)
{
    __shared__ _Float16 At[128 * 64];
    __shared__ _Float16 Btl[256 * 64];
    const int mt = blockIdx.x & 127, dir = blockIdx.x >> 7;
    const int tid = threadIdx.x, lane = tid & 63, w = tid >> 6;
    const int l15 = lane & 15, qd = lane >> 4;
    const int rsub = lane >> 3, pg = lane & 7;
    const int koff = ((pg - rsub) & 7) * 8;
    const int rowbase = mt * 128;
    const _Float16* Bb = Bx + (size_t)dir * 81920 + (w * 64 + rsub) * 320 + koff;

    f32x4 acc[8][4];
    #pragma unroll
    for (int i = 0; i < 8; ++i)
        #pragma unroll
        for (int j = 0; j < 4; ++j) acc[i][j] = (f32x4){0.f, 0.f, 0.f, 0.f};

    #pragma unroll
    for (int kt = 0; kt < 5; ++kt) {
        #pragma unroll
        for (int is = 0; is < 4; ++is)
            async16(x16 + (size_t)(rowbase + w * 32 + is * 8 + rsub) * 320
                        + kt * 64 + koff,
                    &At[(w * 32 + is * 8) * 64]);
        #pragma unroll
        for (int is = 0; is < 8; ++is)
            async16(Bb + (size_t)is * 8 * 320 + kt * 64,
                    &Btl[(w * 64 + is * 8) * 64]);
        __syncthreads();
        #pragma unroll
        for (int s = 0; s < 2; ++s) {
            const int g0 = s * 4 + qd;
            f16x8 af[8];
            #pragma unroll
            for (int i = 0; i < 8; ++i) {
                int R = i * 16 + l15;
                af[i] = *(const f16x8*)&At[R * 64 + ((g0 + R) & 7) * 8];
            }
            #pragma unroll
            for (int j = 0; j < 4; ++j) {
                int C = j * 64 + w * 16 + l15;
                f16x8 bf = *(const f16x8*)&Btl[C * 64 + ((g0 + C) & 7) * 8];
                #pragma unroll
                for (int i = 0; i < 8; ++i)
                    acc[i][j] = __builtin_amdgcn_mfma_f32_16x16x32_f16(
                        af[i], bf, acc[i][j], 0, 0, 0);
            }
        }
        __syncthreads();
    }
    #pragma unroll
    for (int i = 0; i < 8; ++i)
        #pragma unroll
        for (int j = 0; j < 4; ++j) {
            int colp = j * 64 + w * 16 + l15;
            float bias = pb[dir * 256 + colp];
            #pragma unroll
            for (int r = 0; r < 4; ++r) {
                int row = rowbase + i * 16 + qd * 4 + r;
                XP[(size_t)row * 512 + dir * 256 + colp] =
                    (_Float16)(acc[i][j][r] + bias);
            }
        }
}

// ---- one side of one level inside the tree kernel ----
template<int RPP>
__device__ __forceinline__ void do_side(
    const _Float16* __restrict__ Ud, const _Float16* __restrict__ XPd,
    _Float16 (*hSd)[68], _Float16 (*cSd)[68],
    const int (*btl)[32], float* __restrict__ out, int pair0,
    int p0, int p1, int rs0, int rs1, int oc0, int oc1,
    int unit, int l15, int qd, float* hv, float* cv)
{
    constexpr int NI = 2 * RPP;
    f16x8 bfr[2][4];
    #pragma unroll
    for (int s = 0; s < 2; ++s)
        #pragma unroll
        for (int g = 0; g < 4; ++g)
            bfr[s][g] = *(const f16x8*)(Ud + (g * 64 + unit) * 64 + s * 32 + qd * 8);

    f32x4 acc[NI][4];
    #pragma unroll
    for (int i = 0; i < NI; ++i)
        #pragma unroll
        for (int r = 0; r < 4; ++r) {
            int row = i * 16 + qd * 4 + r;
            int pl  = (RPP == 2) ? (row >> 1) : row;
            int pos = (RPP == 2) ? ((row & 1) ? p1 : p0) : p0;
            int bt = btl[pos][pl];
            f16x4 g4 = *(const f16x4*)(XPd + (size_t)bt * 512 + unit * 4);
            acc[i][0][r] = (float)g4[0];
            acc[i][1][r] = (float)g4[1];
            acc[i][2][r] = (float)g4[2];
            acc[i][3][r] = (float)g4[3];
        }

    if (rs0 >= 0) {
        #pragma unroll
        for (int s = 0; s < 2; ++s)
            #pragma unroll
            for (int i = 0; i < NI; ++i) {
                int R = i * 16 + l15;
                int arow = (RPP == 2) ? ((R & ~1) | ((R & 1) ? rs1 : rs0))
                                      : (R * 2 + rs0);
                f16x8 af = *(const f16x8*)&hSd[arow][s * 32 + qd * 8];
                #pragma unroll
                for (int g = 0; g < 4; ++g)
                    acc[i][g] = __builtin_amdgcn_mfma_f32_16x16x32_f16(
                        af, bfr[s][g], acc[i][g], 0, 0, 0);
            }
    }

    #pragma unroll
    for (int i = 0; i < NI; ++i)
        #pragma unroll
        for (int r = 0; r < 4; ++r) {
            int row = i * 16 + qd * 4 + r;
            int pl   = (RPP == 2) ? (row >> 1) : row;
            int slot = (RPP == 2) ? (row & 1) : 0;
            int rs = slot ? rs1 : rs0;
            float cin = (rs >= 0) ? (float)cSd[pl * 2 + rs][unit] : 0.f;
            float I = acc[i][0][r], O = acc[i][1][r],
                  Uu = acc[i][2][r], F = acc[i][3][r];
            float cn = sigm(I) * ftanh(Uu) + sigm(F) * cin;
            float h  = sigm(O) * ftanh(cn);
            int oc = slot ? oc1 : oc0;
            if (oc >= 0) out[(size_t)(pair0 + pl) * 192 + oc + unit] = h;
            hv[i * 4 + r] = h;
            cv[i * 4 + r] = cn;
        }
}

template<int RPP>
__device__ __forceinline__ void wr_state(
    _Float16 (*hSd)[68], _Float16 (*cSd)[68],
    int oc0, int oc1, int unit, int qd, const float* hv, const float* cv)
{
    constexpr int NI = 2 * RPP;
    #pragma unroll
    for (int i = 0; i < NI; ++i)
        #pragma unroll
        for (int r = 0; r < 4; ++r) {
            int row = i * 16 + qd * 4 + r;
            int pl   = (RPP == 2) ? (row >> 1) : row;
            int slot = (RPP == 2) ? (row & 1) : 0;
            int oc = slot ? oc1 : oc0;
            if (oc < 0) {
                hSd[pl * 2 + slot][unit] = (_Float16)hv[i * 4 + r];
                cSd[pl * 2 + slot][unit] = (_Float16)cv[i * 4 + r];
            }
        }
}

__device__ __forceinline__ void do_root(
    const _Float16* __restrict__ Ud, const _Float16* __restrict__ XPd,
    _Float16 (*hSd)[68], _Float16 (*cSd)[68],
    const int (*btl)[32], float* __restrict__ out, int pair0,
    int unit, int l15, int qd)
{
    f16x8 bfr[2][4];
    #pragma unroll
    for (int s = 0; s < 2; ++s)
        #pragma unroll
        for (int g = 0; g < 4; ++g)
            bfr[s][g] = *(const f16x8*)(Ud + (g * 64 + unit) * 64 + s * 32 + qd * 8);

    f32x4 aio[2][3], aF7[2], aF9[2];
    #pragma unroll
    for (int i = 0; i < 2; ++i)
        #pragma unroll
        for (int r = 0; r < 4; ++r) {
            int pl = i * 16 + qd * 4 + r;
            int bt = btl[8][pl];
            f16x4 g4 = *(const f16x4*)(XPd + (size_t)bt * 512 + unit * 4);
            aio[i][0][r] = (float)g4[0];
            aio[i][1][r] = (float)g4[1];
            aio[i][2][r] = (float)g4[2];
            aF7[i][r] = (float)g4[3];
            aF9[i][r] = (float)g4[3];
        }
    #pragma unroll
    for (int s = 0; s < 2; ++s)
        #pragma unroll
        for (int i = 0; i < 2; ++i) {
            int R = i * 16 + l15;
            f16x8 v7 = *(const f16x8*)&hSd[R * 2 + 0][s * 32 + qd * 8];
            f16x8 v9 = *(const f16x8*)&hSd[R * 2 + 1][s * 32 + qd * 8];
            f16x8 vs = v7 + v9;
            aio[i][0] = __builtin_amdgcn_mfma_f32_16x16x32_f16(vs, bfr[s][0], aio[i][0], 0, 0, 0);
            aio[i][1] = __builtin_amdgcn_mfma_f32_16x16x32_f16(vs, bfr[s][1], aio[i][1], 0, 0, 0);
            aio[i][2] = __builtin_amdgcn_mfma_f32_16x16x32_f16(vs, bfr[s][2], aio[i][2], 0, 0, 0);
            aF7[i] = __builtin_amdgcn_mfma_f32_16x16x32_f16(v7, bfr[s][3], aF7[i], 0, 0, 0);
            aF9[i] = __builtin_amdgcn_mfma_f32_16x16x32_f16(v9, bfr[s][3], aF9[i], 0, 0, 0);
        }
    #pragma unroll
    for (int i = 0; i < 2; ++i)
        #pragma unroll
        for (int r = 0; r < 4; ++r) {
            int pl = i * 16 + qd * 4 + r;
            float c7 = (float)cSd[pl * 2 + 0][unit];
            float c9 = (float)cSd[pl * 2 + 1][unit];
            float cn = sigm(aio[i][0][r]) * ftanh(aio[i][2][r])
                     + sigm(aF7[i][r]) * c7 + sigm(aF9[i][r]) * c9;
            float h = sigm(aio[i][1][r]) * ftanh(cn);
            out[(size_t)(pair0 + pl) * 192 + unit] = h;
        }
}

__global__ __launch_bounds__(256, 2) void tree_kernel(
    const int* __restrict__ nb, const int* __restrict__ nt,
    const _Float16* __restrict__ XP, const _Float16* __restrict__ Upk,
    float* __restrict__ out)
{
    __shared__ _Float16 hS[2][64][68];    // [dir][pair_l*2+slot][unit], pad 68
    __shared__ _Float16 cS[2][64][68];
    __shared__ int btl[16][32];           // [pos][pair_l] -> nb*512+nt

    const int tid = threadIdx.x, lane = tid & 63, w = tid >> 6;
    const int l15 = lane & 15, qd = lane >> 4;
    const int unit = w * 16 + l15;
    const int pair0 = blockIdx.x * 32;

    for (int e = tid; e < 512; e += 256) {
        int pos = e >> 5, pl = e & 31;
        int node = (pair0 + pl) * 16 + pos;
        btl[pos][pl] = nb[node] * 512 + nt[node];
    }
    __syncthreads();

    float hv[2][16], cv[2][16];

    for (int t = 0; t < 9; ++t) {
        const bool root = (t == 8);
        // ---- up ----
        if (!root) {
            if (t < 7)
                do_side<2>(Upk, XP, hS[0], cS[0], btl, out, pair0,
                           t, 15 - t, t ? 0 : -1, t ? 1 : -1, -1, -1,
                           unit, l15, qd, hv[0], cv[0]);
            else
                do_side<1>(Upk, XP, hS[0], cS[0], btl, out, pair0,
                           7, 7, 0, 0, -1, -1, unit, l15, qd, hv[0], cv[0]);
        } else {
            do_root(Upk, XP, hS[0], cS[0], btl, out, pair0, unit, l15, qd);
        }
        // ---- down ----
        if (t == 0)
            do_side<1>(Upk + 16384, XP + 256, hS[1], cS[1], btl, out, pair0,
                       8, 8, -1, -1, -1, -1, unit, l15, qd, hv[1], cv[1]);
        else if (t == 8)
            do_side<1>(Upk + 16384, XP + 256, hS[1], cS[1], btl, out, pair0,
                       0, 0, 0, 0, 64, 64, unit, l15, qd, hv[1], cv[1]);
        else
            do_side<2>(Upk + 16384, XP + 256, hS[1], cS[1], btl, out, pair0,
                       8 - t, 8 + t, 0, (t == 1) ? 0 : 1,
                       -1, (t == 7) ? 128 : -1,
                       unit, l15, qd, hv[1], cv[1]);

        __syncthreads();   // all LDS state reads of level t complete

        if (!root) {
            if (t < 7) wr_state<2>(hS[0], cS[0], -1, -1, unit, qd, hv[0], cv[0]);
            else       wr_state<1>(hS[0], cS[0], -1, -1, unit, qd, hv[0], cv[0]);
        }
        if (t == 0)
            wr_state<1>(hS[1], cS[1], -1, -1, unit, qd, hv[1], cv[1]);
        else if (t < 8)
            wr_state<2>(hS[1], cS[1], -1, (t == 7) ? 128 : -1,
                        unit, qd, hv[1], cv[1]);
        // t==8 down: out only, no state

        __syncthreads();   // writes visible for level t+1
    }
}

extern "C" void kernel_launch(void* const* d_in, const int* in_sizes, int n_in,
                              void* d_out, int out_size, void* d_ws, size_t ws_size,
                              hipStream_t stream)
{
    const float* tok  = (const float*)d_in[0];
    const float* ohp  = (const float*)d_in[1];
    const float* dep  = (const float*)d_in[2];
    const int*   nb   = (const int*)d_in[3];
    const int*   nt   = (const int*)d_in[4];
    const float* Wi_u = (const float*)d_in[13];
    const float* Ui_u = (const float*)d_in[14];
    const float* bi_u = (const float*)d_in[15];
    const float* Wf_u = (const float*)d_in[16];
    const float* Uf_u = (const float*)d_in[17];
    const float* bf_u = (const float*)d_in[18];
    const float* Wi_d = (const float*)d_in[19];
    const float* Ui_d = (const float*)d_in[20];
    const float* bi_d = (const float*)d_in[21];
    const float* Wf_d = (const float*)d_in[22];
    const float* Uf_d = (const float*)d_in[23];
    const float* bf_d = (const float*)d_in[24];

    char* ws = (char*)d_ws;
    _Float16* Bx  = (_Float16*)(ws);                    // 320 KB
    _Float16* Upk = (_Float16*)(ws + 0x50000);          // 64 KB
    float*    pb  = (float*)   (ws + 0x60000);          // 2 KB
    _Float16* x16 = (_Float16*)(ws + (1u  << 20));      // 10 MB
    _Float16* XP  = (_Float16*)(ws + (12u << 20));      // 16 MB
    float* out = (float*)d_out;

    pack_all<<<768, 256, 0, stream>>>(Wi_u, Ui_u, bi_u, Wf_u, Uf_u, bf_u,
                                      Wi_d, Ui_d, bi_d, Wf_d, Uf_d, bf_d,
                                      Bx, Upk, pb);
    build_x16<<<2560, 256, 0, stream>>>(tok, ohp, dep, x16);
    xp_gemm<<<256, 256, 0, stream>>>(x16, Bx, pb, XP);
    tree_kernel<<<512, 256, 0, stream>>>(nb, nt, XP, Upk, out);

    (void)in_sizes; (void)n_in; (void)out_size; (void)ws_size;
}